// Round 1
// baseline (288.415 us; speedup 1.0000x reference)
//
#include <hip/hip_runtime.h>
#include <hip/hip_bf16.h>
#include <stdint.h>

#define IN_F 1024
#define OUT_F 1024
#define NB 8
#define KDIM (IN_F + IN_F * NB)  /* 9216 */
#define NROWS 4096

typedef __attribute__((ext_vector_type(8))) short bf16x8;
typedef __attribute__((ext_vector_type(4))) float f32x4;

// Cox-de Boor cubic basis, matches reference exactly (grid=5, order=3, range [-1,1], EPS=1e-8).
__device__ __forceinline__ void bspline8(float x, float b8[8]) {
  float t[12];
#pragma unroll
  for (int j = 0; j < 12; ++j) t[j] = (float)(j - 3) * 0.4f - 1.0f;  // constant-folded
  float b[11];
#pragma unroll
  for (int j = 0; j < 11; ++j) b[j] = (x >= t[j] && x < t[j + 1]) ? 1.0f : 0.0f;
#pragma unroll
  for (int k = 1; k <= 3; ++k) {
#pragma unroll
    for (int j = 0; j + k < 11; ++j) {
      float rl = 1.0f / (t[j + k] - t[j] + 1e-8f);       // compile-time constants
      float rr = 1.0f / (t[j + k + 1] - t[j + 1] + 1e-8f);
      b[j] = (x - t[j]) * rl * b[j] + (t[j + k + 1] - x) * rr * b[j + 1];
    }
  }
#pragma unroll
  for (int c = 0; c < 8; ++c) b8[c] = b[c];
}

// A[n, 0:1024] = silu(x[n,:]);  A[n, 1024 + i*8 + b] = basis_b(x[n,i]).  bf16 out.
__global__ void prep_kernel(const float* __restrict__ x, __hip_bfloat16* __restrict__ A) {
  int idx = blockIdx.x * 256 + threadIdx.x;  // 4096*1024 threads
  int n = idx >> 10;
  int i = idx & 1023;
  float xv = x[idx];
  float s = xv / (1.0f + __expf(-xv));
  __hip_bfloat16* row = A + (size_t)n * KDIM;
  row[i] = __float2bfloat16(s);
  float b8[8];
  bspline8(xv, b8);
  alignas(16) __hip_bfloat16 tmp[8];
#pragma unroll
  for (int c = 0; c < 8; ++c) tmp[c] = __float2bfloat16(b8[c]);
  *(bf16x8*)(row + IN_F + i * 8) = *(const bf16x8*)tmp;  // 16B coalesced store
}

// W[o, 0:1024] = base_weight[o,:]; W[o, 1024:] = spline_weight[o,:,:] flat.  bf16.
__global__ void wconv_kernel(const float* __restrict__ bw, const float* __restrict__ sw,
                             __hip_bfloat16* __restrict__ W) {
  int idx = blockIdx.x * 256 + threadIdx.x;  // 1024*9216 threads
  int o = idx / KDIM;
  int k = idx - o * KDIM;
  float v = (k < IN_F) ? bw[o * IN_F + k] : sw[(size_t)o * (IN_F * NB) + (k - IN_F)];
  W[idx] = __float2bfloat16(v);
}

// C[4096,1024] = A[4096,9216] @ W[1024,9216]^T + bias.  m97-style 128x128x32 MFMA tile.
__global__ __launch_bounds__(256) void gemm_kernel(const __hip_bfloat16* __restrict__ A,
                                                   const __hip_bfloat16* __restrict__ W,
                                                   const float* __restrict__ bias,
                                                   float* __restrict__ out) {
  __shared__ __hip_bfloat16 lA[128 * 32];
  __shared__ __hip_bfloat16 lB[128 * 32];
  const int tid = threadIdx.x;
  const int wave = tid >> 6;
  const int lane = tid & 63;
  const int bm = blockIdx.x * 128;
  const int bn = blockIdx.y * 128;
  const int lrow = lane >> 2;           // 0..15: row within 16-row staging chunk
  const int lcolb = (lane & 3) * 8;     // element offset in K (x8 bf16 = 16B)
  const int wm = (wave & 1) * 64;       // 2x2 wave grid -> 64x64 per wave
  const int wn = (wave >> 1) * 64;
  const int r = lane & 15;
  const int quad = lane >> 4;

  f32x4 acc[4][4];
#pragma unroll
  for (int a = 0; a < 4; ++a)
#pragma unroll
    for (int b = 0; b < 4; ++b) acc[a][b] = (f32x4){0.f, 0.f, 0.f, 0.f};

  for (int k0 = 0; k0 < KDIM; k0 += 32) {
    // Stage A-tile and B-tile: each wave issues 2x2 global_load_lds_dwordx4.
    // LDS layout [128][32] bf16 unpadded: dest = wave-uniform base + lane*16 (HW rule).
#pragma unroll
    for (int h = 0; h < 2; ++h) {
      const int rowbase = wave * 32 + h * 16;
      const int row = rowbase + lrow;
      const __hip_bfloat16* ga = A + (size_t)(bm + row) * KDIM + k0 + lcolb;
      const __hip_bfloat16* gb = W + (size_t)(bn + row) * KDIM + k0 + lcolb;
      __builtin_amdgcn_global_load_lds((const __attribute__((address_space(1))) void*)ga,
                                       (__attribute__((address_space(3))) void*)(lA + rowbase * 32),
                                       16, 0, 0);
      __builtin_amdgcn_global_load_lds((const __attribute__((address_space(1))) void*)gb,
                                       (__attribute__((address_space(3))) void*)(lB + rowbase * 32),
                                       16, 0, 0);
    }
    __syncthreads();  // drains vmcnt for global_load_lds

    // Fragments: A-operand lane map m=lane&15, k=quad*8+j (16B ds_read_b128 each).
    bf16x8 af[4], bfr[4];
#pragma unroll
    for (int t = 0; t < 4; ++t) {
      af[t] = *(const bf16x8*)(lA + (wm + t * 16 + r) * 32 + quad * 8);
      bfr[t] = *(const bf16x8*)(lB + (wn + t * 16 + r) * 32 + quad * 8);
    }
#pragma unroll
    for (int tm = 0; tm < 4; ++tm)
#pragma unroll
      for (int tn = 0; tn < 4; ++tn)
        acc[tm][tn] =
            __builtin_amdgcn_mfma_f32_16x16x32_bf16(af[tm], bfr[tn], acc[tm][tn], 0, 0, 0);
    __syncthreads();
  }

  // Epilogue: C/D map col=lane&15, row=quad*4+reg (m89-verified). Add bias, fp32 store.
#pragma unroll
  for (int tm = 0; tm < 4; ++tm) {
#pragma unroll
    for (int tn = 0; tn < 4; ++tn) {
      const int col = bn + wn + tn * 16 + r;
      const float bv = bias[col];
#pragma unroll
      for (int reg = 0; reg < 4; ++reg) {
        const int rowi = bm + wm + tm * 16 + quad * 4 + reg;
        out[(size_t)rowi * OUT_F + col] = acc[tm][tn][reg] + bv;
      }
    }
  }
}

// Emergency fallback if ws is too small for A+W (fp32, slow but correct).
__global__ void kan_fallback(const float* __restrict__ x, const float* __restrict__ bw,
                             const float* __restrict__ bb, const float* __restrict__ sw,
                             float* __restrict__ out) {
  __shared__ float act[KDIM];
  int n = blockIdx.x;
  for (int i = threadIdx.x; i < IN_F; i += 256) {
    float xv = x[(size_t)n * IN_F + i];
    act[i] = xv / (1.0f + __expf(-xv));
    float b8[8];
    bspline8(xv, b8);
#pragma unroll
    for (int c = 0; c < 8; ++c) act[IN_F + i * 8 + c] = b8[c];
  }
  __syncthreads();
  for (int o = threadIdx.x; o < OUT_F; o += 256) {
    float s = bb[o];
    const float* wbp = bw + (size_t)o * IN_F;
    for (int k = 0; k < IN_F; ++k) s += act[k] * wbp[k];
    const float* wsp = sw + (size_t)o * (IN_F * NB);
    for (int k = 0; k < IN_F * NB; ++k) s += act[IN_F + k] * wsp[k];
    out[(size_t)n * OUT_F + o] = s;
  }
}

extern "C" void kernel_launch(void* const* d_in, const int* in_sizes, int n_in, void* d_out,
                              int out_size, void* d_ws, size_t ws_size, hipStream_t stream) {
  const float* x = (const float*)d_in[0];
  const float* bw = (const float*)d_in[1];
  const float* bb = (const float*)d_in[2];
  const float* sw = (const float*)d_in[3];
  float* out = (float*)d_out;

  const size_t needA = (size_t)NROWS * KDIM * 2;  // 75.5 MB
  const size_t needW = (size_t)OUT_F * KDIM * 2;  // 18.9 MB
  if (ws_size < needA + needW) {
    kan_fallback<<<NROWS, 256, 0, stream>>>(x, bw, bb, sw, out);
    return;
  }
  __hip_bfloat16* A = (__hip_bfloat16*)d_ws;
  __hip_bfloat16* W = (__hip_bfloat16*)((char*)d_ws + needA);

  prep_kernel<<<(NROWS * IN_F) / 256, 256, 0, stream>>>(x, A);
  wconv_kernel<<<(OUT_F * KDIM) / 256, 256, 0, stream>>>(bw, sw, W);
  dim3 g(NROWS / 128, OUT_F / 128);
  gemm_kernel<<<g, 256, 0, stream>>>(A, W, bb, out);
}